// Round 7
// baseline (205.714 us; speedup 1.0000x reference)
//
#include <hip/hip_runtime.h>
#include <hip/hip_bf16.h>

typedef signed char i8;
typedef int v4i __attribute__((ext_vector_type(4)));

#define LSTR 80  // LDS row stride (bytes) for gemm2 staging
#define MFMA_I8 __builtin_amdgcn_mfma_i32_16x16x64_i8

// ---------------- merged |w| abs-sum (fp64, deterministic layout) ----------------
__global__ __launch_bounds__(256) void k_abssum_all(const float* __restrict__ w0, const float* __restrict__ w1,
                                                    const float* __restrict__ w2, const float* __restrict__ w3,
                                                    const float* __restrict__ w4, double* __restrict__ partial) {
  int b = blockIdx.x;
  const float* w; int n, nb, bg;
  if (b < 256)      { w = w0; n = 4194304; nb = 256; bg = b; }
  else if (b < 272) { w = w1; n = 32768;   nb = 16;  bg = b - 256; }
  else if (b < 288) { w = w2; n = 32768;   nb = 16;  bg = b - 272; }
  else if (b < 304) { w = w3; n = 32768;   nb = 16;  bg = b - 288; }
  else              { w = w4; n = 2097152; nb = 128; bg = b - 304; }
  __shared__ double sd[256];
  double acc = 0.0;
  for (int i = bg * 256 + threadIdx.x; i < n; i += nb * 256) acc += (double)fabsf(w[i]);
  sd[threadIdx.x] = acc;
  __syncthreads();
  for (int s = 128; s > 0; s >>= 1) {
    if (threadIdx.x < s) sd[threadIdx.x] += sd[threadIdx.x + s];
    __syncthreads();
  }
  if (threadIdx.x == 0) partial[b] = sd[0];
}

__global__ void k_finalize(const double* __restrict__ partial, float* __restrict__ scales) {
  int m = threadIdx.x;
  if (m >= 5) return;
  const int off[6] = {0, 256, 272, 288, 304, 432};
  const double cnt[5] = {4194304.0, 32768.0, 32768.0, 32768.0, 2097152.0};
  double s = 0.0;
  for (int i = off[m]; i < off[m + 1]; ++i) s += partial[i];
  scales[m] = fmaxf((float)(s / cnt[m]), 1e-5f);
}

// ---------------- merged ternary weight quant ----------------
__global__ __launch_bounds__(256) void k_wquant_all(const float* __restrict__ w0, const float* __restrict__ w1,
                                                    const float* __restrict__ w2, const float* __restrict__ w3,
                                                    const float* __restrict__ w4, const float* __restrict__ scales,
                                                    i8* __restrict__ tin, i8* __restrict__ t2, i8* __restrict__ tout) {
  int b = blockIdx.x;
  const float* w; i8* t; int m, n;
  if (b < 4096)      { w = w0; t = tin;          m = 0; n = 4194304; }
  else if (b < 4128) { w = w1; t = t2;           m = 1; n = 32768; b -= 4096; }
  else if (b < 4160) { w = w2; t = t2 + 32768;   m = 2; n = 32768; b -= 4128; }
  else if (b < 4192) { w = w3; t = t2 + 65536;   m = 3; n = 32768; b -= 4160; }
  else               { w = w4; t = tout;         m = 4; n = 2097152; b -= 4192; }
  int idx = (b * 256 + threadIdx.x) * 4;
  if (idx >= n) return;
  float scale = scales[m];
  float4 v = *(const float4*)(w + idx);
  char4 q;
  q.x = (i8)fminf(fmaxf(rintf(v.x / scale), -1.f), 1.f);
  q.y = (i8)fminf(fmaxf(rintf(v.y / scale), -1.f), 1.f);
  q.z = (i8)fminf(fmaxf(rintf(v.z / scale), -1.f), 1.f);
  q.w = (i8)fminf(fmaxf(rintf(v.w / scale), -1.f), 1.f);
  *(char4*)(t + idx) = q;
}

// ---------------- per-row activation quant (bit-exact vs reference) ----------------
template <int W>
__global__ __launch_bounds__(256) void k_actquant(const float* __restrict__ x,
                                                  i8* __restrict__ q, float* __restrict__ srow) {
  constexpr int E = W / 256;
  const int r = blockIdx.x, tid = threadIdx.x;
  const float* xr = x + (size_t)r * W;
  float v[E];
  float m = 0.f;
#pragma unroll
  for (int j = 0; j < E; j += 4) {
    float4 t = *(const float4*)(xr + tid * E + j);
    v[j] = t.x; v[j + 1] = t.y; v[j + 2] = t.z; v[j + 3] = t.w;
    m = fmaxf(m, fmaxf(fmaxf(fabsf(t.x), fabsf(t.y)), fmaxf(fabsf(t.z), fabsf(t.w))));
  }
  __shared__ float sm[4];
  __shared__ float sbc;
#pragma unroll
  for (int off = 32; off > 0; off >>= 1) m = fmaxf(m, __shfl_xor(m, off));
  if ((tid & 63) == 0) sm[tid >> 6] = m;
  __syncthreads();
  if (tid == 0) {
    float mm = fmaxf(fmaxf(sm[0], sm[1]), fmaxf(sm[2], sm[3]));
    float s = 127.0f / fmaxf(mm, 1e-5f);
    sbc = s;
    srow[r] = s;
  }
  __syncthreads();
  float s = sbc;
#pragma unroll
  for (int j = 0; j < E; j += 4) {
    char4 c;
    c.x = (i8)fminf(fmaxf(rintf(v[j] * s), -128.f), 127.f);
    c.y = (i8)fminf(fmaxf(rintf(v[j + 1] * s), -128.f), 127.f);
    c.z = (i8)fminf(fmaxf(rintf(v[j + 2] * s), -128.f), 127.f);
    c.w = (i8)fminf(fmaxf(rintf(v[j + 3] * s), -128.f), 127.f);
    *(char4*)(q + (size_t)r * W + tid * E + j) = c;
  }
}

// ---------------- GEMM1: 256x128, no-LDS, direct global->VGPR fragments, dbuf 1 tile ----------------
__global__ __launch_bounds__(512) void k_gemm1(const i8* __restrict__ qx, const i8* __restrict__ tin,
                                               const float* __restrict__ sx, const float* __restrict__ scales,
                                               float* __restrict__ gated) {
  __shared__ float frow[256];
  const int tid = threadIdx.x;
  const int r0 = blockIdx.x * 256, c0 = blockIdx.y * 128;
  if (tid < 256) frow[tid] = scales[0] / sx[r0 + tid];
  __syncthreads();
  const int lane = tid & 63, wv = tid >> 6;
  const int wm = wv >> 1, wn = wv & 1;   // wave tile: rows wm*64, cols wn*64
  const int lo = lane & 15, hi = lane >> 4;
  int offA[4], offG[4], offV[4];
#pragma unroll
  for (int m = 0; m < 4; ++m) offA[m] = (r0 + wm * 64 + m * 16 + lo) * 1024 + hi * 16;
#pragma unroll
  for (int n = 0; n < 4; ++n) {
    offG[n] = (c0 + wn * 64 + n * 16 + lo) * 1024 + hi * 16;
    offV[n] = (2048 + c0 + wn * 64 + n * 16 + lo) * 1024 + hi * 16;
  }
  v4i accg[4][4], accv[4][4];
#pragma unroll
  for (int m = 0; m < 4; ++m)
#pragma unroll
    for (int n = 0; n < 4; ++n) {
      accg[m][n] = (v4i){0, 0, 0, 0};
      accv[m][n] = (v4i){0, 0, 0, 0};
    }
  v4i a0[4], g0[4], v0[4], a1[4], g1[4], v1[4];

#define LD1(t, A, G, V)                                                         \
  {                                                                             \
    _Pragma("unroll") for (int m = 0; m < 4; ++m)                               \
        A[m] = *(const v4i*)(qx + offA[m] + (t) * 64);                          \
    _Pragma("unroll") for (int n = 0; n < 4; ++n) {                             \
      G[n] = *(const v4i*)(tin + offG[n] + (t) * 64);                           \
      V[n] = *(const v4i*)(tin + offV[n] + (t) * 64);                           \
    }                                                                           \
  }
#define FM1(A, G, V)                                                            \
  {                                                                             \
    _Pragma("unroll") for (int n = 0; n < 4; ++n)                               \
        _Pragma("unroll") for (int m = 0; m < 4; ++m) {                         \
      accg[m][n] = MFMA_I8(A[m], G[n], accg[m][n], 0, 0, 0);                    \
      accv[m][n] = MFMA_I8(A[m], V[n], accv[m][n], 0, 0, 0);                    \
    }                                                                           \
  }

  LD1(0, a0, g0, v0);
#pragma unroll
  for (int t = 0; t < 16; t += 2) {
    if (t + 1 < 16) LD1(t + 1, a1, g1, v1);
    FM1(a0, g0, v0);
    if (t + 2 < 16) LD1(t + 2, a0, g0, v0);
    if (t + 1 < 16) FM1(a1, g1, v1);
  }
#undef LD1
#undef FM1

#pragma unroll
  for (int m = 0; m < 4; ++m)
#pragma unroll
    for (int n = 0; n < 4; ++n)
#pragma unroll
      for (int rg = 0; rg < 4; ++rg) {
        int row = wm * 64 + m * 16 + hi * 4 + rg;
        int col = wn * 64 + n * 16 + lo;
        float f = frow[row];
        float g = (float)accg[m][n][rg] * f;
        float v = (float)accv[m][n][rg] * f;
        float sg = 1.0f / (1.0f + expf(-g));
        gated[(size_t)(r0 + row) * 2048 + c0 + col] = g * sg * v;
      }
}

// ---------------- fused causal depthwise conv + act-quant, 8 rows/block, all-in-regs ----------------
__global__ __launch_bounds__(256) void k_convq(const float* __restrict__ g, const float* __restrict__ cw,
                                               const float* __restrict__ cb, float* __restrict__ xo,
                                               i8* __restrict__ q, float* __restrict__ srow) {
  const int tid = threadIdx.x;
  const int r0 = blockIdx.x * 8;
  const int l0 = r0 & 2047;
  const int ch = tid * 8;
  const int lane = tid & 63, wv = tid >> 6;
  float wt[4][8];
#pragma unroll
  for (int j = 0; j < 8; ++j) {
    float4 w = *(const float4*)(cw + (ch + j) * 4);
    wt[0][j] = w.x; wt[1][j] = w.y; wt[2][j] = w.z; wt[3][j] = w.w;
  }
  float bias[8];
  {
    float4 b0 = *(const float4*)(cb + ch), b1 = *(const float4*)(cb + ch + 4);
    bias[0] = b0.x; bias[1] = b0.y; bias[2] = b0.z; bias[3] = b0.w;
    bias[4] = b1.x; bias[5] = b1.y; bias[6] = b1.z; bias[7] = b1.w;
  }
  const float* gb = g + (size_t)r0 * 2048 + ch;
  float wm3[8], wm2[8], wm1[8];
  if (l0 != 0) {
    float4 a, b;
    a = *(const float4*)(gb - 3 * 2048); b = *(const float4*)(gb - 3 * 2048 + 4);
    wm3[0]=a.x; wm3[1]=a.y; wm3[2]=a.z; wm3[3]=a.w; wm3[4]=b.x; wm3[5]=b.y; wm3[6]=b.z; wm3[7]=b.w;
    a = *(const float4*)(gb - 2 * 2048); b = *(const float4*)(gb - 2 * 2048 + 4);
    wm2[0]=a.x; wm2[1]=a.y; wm2[2]=a.z; wm2[3]=a.w; wm2[4]=b.x; wm2[5]=b.y; wm2[6]=b.z; wm2[7]=b.w;
    a = *(const float4*)(gb - 1 * 2048); b = *(const float4*)(gb - 1 * 2048 + 4);
    wm1[0]=a.x; wm1[1]=a.y; wm1[2]=a.z; wm1[3]=a.w; wm1[4]=b.x; wm1[5]=b.y; wm1[6]=b.z; wm1[7]=b.w;
  } else {
#pragma unroll
    for (int j = 0; j < 8; ++j) { wm3[j] = 0.f; wm2[j] = 0.f; wm1[j] = 0.f; }
  }
  float* xop = xo + (size_t)r0 * 2048 + ch;
  float y[8][8];
  float rowmax[8];
#pragma unroll
  for (int l = 0; l < 8; ++l) {
    float cur[8];
    {
      float4 a = *(const float4*)(gb + l * 2048), b = *(const float4*)(gb + l * 2048 + 4);
      cur[0]=a.x; cur[1]=a.y; cur[2]=a.z; cur[3]=a.w; cur[4]=b.x; cur[5]=b.y; cur[6]=b.z; cur[7]=b.w;
    }
    float m = 0.f;
#pragma unroll
    for (int j = 0; j < 8; ++j) {
      float v = bias[j];
      v = fmaf(wt[0][j], wm3[j], v);
      v = fmaf(wt[1][j], wm2[j], v);
      v = fmaf(wt[2][j], wm1[j], v);
      v = fmaf(wt[3][j], cur[j], v);
      y[l][j] = v;
      m = fmaxf(m, fabsf(v));
    }
    rowmax[l] = m;
    *(float4*)(xop + l * 2048) = make_float4(y[l][0], y[l][1], y[l][2], y[l][3]);
    *(float4*)(xop + l * 2048 + 4) = make_float4(y[l][4], y[l][5], y[l][6], y[l][7]);
#pragma unroll
    for (int j = 0; j < 8; ++j) { wm3[j] = wm2[j]; wm2[j] = wm1[j]; wm1[j] = cur[j]; }
  }
  __shared__ float sred[8][4];
  __shared__ float sscale[8];
#pragma unroll
  for (int l = 0; l < 8; ++l) {
    float m = rowmax[l];
#pragma unroll
    for (int off = 32; off > 0; off >>= 1) m = fmaxf(m, __shfl_xor(m, off));
    if (lane == 0) sred[l][wv] = m;
  }
  __syncthreads();
  if (tid < 8) {
    float mm = fmaxf(fmaxf(sred[tid][0], sred[tid][1]), fmaxf(sred[tid][2], sred[tid][3]));
    float s = 127.0f / fmaxf(mm, 1e-5f);
    sscale[tid] = s;
    srow[r0 + tid] = s;
  }
  __syncthreads();
  i8* qp = q + (size_t)r0 * 2048 + ch;
#pragma unroll
  for (int l = 0; l < 8; ++l) {
    float s = sscale[l];
    char4 c0q, c1q;
    c0q.x = (i8)fminf(fmaxf(rintf(y[l][0] * s), -128.f), 127.f);
    c0q.y = (i8)fminf(fmaxf(rintf(y[l][1] * s), -128.f), 127.f);
    c0q.z = (i8)fminf(fmaxf(rintf(y[l][2] * s), -128.f), 127.f);
    c0q.w = (i8)fminf(fmaxf(rintf(y[l][3] * s), -128.f), 127.f);
    c1q.x = (i8)fminf(fmaxf(rintf(y[l][4] * s), -128.f), 127.f);
    c1q.y = (i8)fminf(fmaxf(rintf(y[l][5] * s), -128.f), 127.f);
    c1q.z = (i8)fminf(fmaxf(rintf(y[l][6] * s), -128.f), 127.f);
    c1q.w = (i8)fminf(fmaxf(rintf(y[l][7] * s), -128.f), 127.f);
    *(char4*)(qp + l * 2048) = c0q;
    *(char4*)(qp + l * 2048 + 4) = c1q;
  }
}

// ---------------- GEMM2: K-split i32 partials ----------------
__global__ __launch_bounds__(256) void k_gemm2(const i8* __restrict__ q2, const i8* __restrict__ t2,
                                               int* __restrict__ ipart) {
  __shared__ i8 As[64 * LSTR];
  __shared__ i8 Bs[48 * LSTR];
  const int tid = threadIdx.x;
  const int r0 = blockIdx.x * 64;
  const int kb = blockIdx.y * 1024;
  const int lrow = tid >> 2, lk = (tid & 3) * 16;
  const int lane = tid & 63, wv = tid >> 6;
  const int fr = lane & 15, fk = (lane >> 4) * 16;
  v4i acc[3];
#pragma unroll
  for (int s = 0; s < 3; ++s) acc[s] = (v4i){0, 0, 0, 0};
  for (int ks = 0; ks < 16; ++ks) {
    const int k0 = kb + ks * 64;
    __syncthreads();
    *(v4i*)&As[lrow * LSTR + lk] = *(const v4i*)&q2[(size_t)(r0 + lrow) * 2048 + k0 + lk];
    if (tid < 192)
      *(v4i*)&Bs[(tid >> 2) * LSTR + (tid & 3) * 16] = *(const v4i*)&t2[(size_t)(tid >> 2) * 2048 + k0 + (tid & 3) * 16];
    __syncthreads();
    v4i a = *(const v4i*)&As[(wv * 16 + fr) * LSTR + fk];
#pragma unroll
    for (int s = 0; s < 3; ++s) {
      v4i b = *(const v4i*)&Bs[(s * 16 + fr) * LSTR + fk];
      acc[s] = MFMA_I8(a, b, acc[s], 0, 0, 0);
    }
  }
#pragma unroll
  for (int s = 0; s < 3; ++s)
#pragma unroll
    for (int rg = 0; rg < 4; ++rg) {
      int row = wv * 16 + (lane >> 4) * 4 + rg;
      int col = s * 16 + (lane & 15);
      ipart[(size_t)blockIdx.y * 196608 + (size_t)(r0 + row) * 48 + col] = acc[s][rg];
    }
}

// ---------------- combine partials, dequant, build A_d / delta*B / C transposed ----------------
__global__ __launch_bounds__(256) void k_xform(const int* __restrict__ ip, const float* __restrict__ s2,
                                               const float* __restrict__ scales, const float* __restrict__ dbias,
                                               const float* __restrict__ logA, float* __restrict__ At,
                                               float* __restrict__ dBt, float* __restrict__ Ct) {
  int idx = blockIdx.x * 256 + threadIdx.x;
  int r = idx >> 4, n = idx & 15;
  int b = r >> 11, l = r & 2047;
  float fr = 1.0f / s2[r];
  int base = r * 48;
  float dd = (float)(ip[base + n] + ip[196608 + base + n]) * (scales[1] * fr) + dbias[n];
  float Bv = (float)(ip[base + 16 + n] + ip[196608 + base + 16 + n]) * (scales[2] * fr);
  float Cv = (float)(ip[base + 32 + n] + ip[196608 + base + 32 + n]) * (scales[3] * fr);
  int o = ((b * 16 + n) << 11) | l;
  At[o] = expf(dd * logA[n]);
  dBt[o] = dd * Bv;
  Ct[o] = Cv;
}

// ---------------- parallel scan over time per (b,n) ----------------
__global__ __launch_bounds__(256) void k_scan(const float* __restrict__ At, const float* __restrict__ dBt,
                                              const float* __restrict__ Ct, float* __restrict__ ch) {
  const int i = threadIdx.x;
  const int base = blockIdx.x << 11;
  float a[8], db[8], c[8];
  {
    const float4* p = (const float4*)(At + base + i * 8);
    float4 t0 = p[0], t1 = p[1];
    a[0]=t0.x; a[1]=t0.y; a[2]=t0.z; a[3]=t0.w; a[4]=t1.x; a[5]=t1.y; a[6]=t1.z; a[7]=t1.w;
  }
  {
    const float4* p = (const float4*)(dBt + base + i * 8);
    float4 t0 = p[0], t1 = p[1];
    db[0]=t0.x; db[1]=t0.y; db[2]=t0.z; db[3]=t0.w; db[4]=t1.x; db[5]=t1.y; db[6]=t1.z; db[7]=t1.w;
  }
  {
    const float4* p = (const float4*)(Ct + base + i * 8);
    float4 t0 = p[0], t1 = p[1];
    c[0]=t0.x; c[1]=t0.y; c[2]=t0.z; c[3]=t0.w; c[4]=t1.x; c[5]=t1.y; c[6]=t1.z; c[7]=t1.w;
  }
  float Ac = 1.f, Bc = 0.f;
#pragma unroll
  for (int j = 0; j < 8; ++j) { Bc = a[j] * Bc + db[j]; Ac *= a[j]; }
  __shared__ float sA[256], sB[256];
  sA[i] = Ac; sB[i] = Bc;
  __syncthreads();
  for (int off = 1; off < 256; off <<= 1) {
    float pA = 1.f, pB = 0.f;
    if (i >= off) { pA = sA[i - off]; pB = sB[i - off]; }
    __syncthreads();
    Bc = Ac * pB + Bc;
    Ac = Ac * pA;
    sA[i] = Ac; sB[i] = Bc;
    __syncthreads();
  }
  float h = (i > 0) ? sB[i - 1] : 0.f;
  float o[8];
#pragma unroll
  for (int j = 0; j < 8; ++j) { h = a[j] * h + db[j]; o[j] = c[j] * h; }
  float4* po = (float4*)(ch + base + i * 8);
  po[0] = make_float4(o[0], o[1], o[2], o[3]);
  po[1] = make_float4(o[4], o[5], o[6], o[7]);
}

// ---------------- y_inner scaling + act-quant, 8 rows/block, all-in-regs ----------------
__global__ __launch_bounds__(256) void k_yq(const float* __restrict__ xin, const float* __restrict__ chb,
                                            const float* __restrict__ Dp, i8* __restrict__ q,
                                            float* __restrict__ srow) {
  const int tid = threadIdx.x;
  const int r0 = blockIdx.x * 8;
  const int b = r0 >> 11, l0 = r0 & 2047;
  const int lane = tid & 63, wv = tid >> 6;
  __shared__ float ssig[8 * 16];
  __shared__ float ssg[8];
  __shared__ float sred[8][4];
  __shared__ float sscale[8];
  if (tid < 128) {
    int n = tid >> 3, li = tid & 7;
    ssig[li * 16 + n] = chb[((size_t)(b * 16 + n) << 11) | (l0 + li)];
  }
  __syncthreads();
  if (tid < 8) {
    float s = 0.f;
    for (int n = 0; n < 16; ++n) s += ssig[tid * 16 + n];
    ssg[tid] = 1.0f / (1.0f + expf(-s));
  }
  __syncthreads();
  const int ch = tid * 8;
  float dreg[8];
  {
    float4 d0 = *(const float4*)(Dp + ch), d1 = *(const float4*)(Dp + ch + 4);
    dreg[0]=d0.x; dreg[1]=d0.y; dreg[2]=d0.z; dreg[3]=d0.w;
    dreg[4]=d1.x; dreg[5]=d1.y; dreg[6]=d1.z; dreg[7]=d1.w;
  }
  const float* xr = xin + (size_t)r0 * 2048 + ch;
  float y[8][8];
  float rowmax[8];
#pragma unroll
  for (int l = 0; l < 8; ++l) {
    float sg = ssg[l];
    float4 a = *(const float4*)(xr + l * 2048);
    float4 c = *(const float4*)(xr + l * 2048 + 4);
    y[l][0] = a.x * (sg + dreg[0]);
    y[l][1] = a.y * (sg + dreg[1]);
    y[l][2] = a.z * (sg + dreg[2]);
    y[l][3] = a.w * (sg + dreg[3]);
    y[l][4] = c.x * (sg + dreg[4]);
    y[l][5] = c.y * (sg + dreg[5]);
    y[l][6] = c.z * (sg + dreg[6]);
    y[l][7] = c.w * (sg + dreg[7]);
    float m = 0.f;
#pragma unroll
    for (int j = 0; j < 8; ++j) m = fmaxf(m, fabsf(y[l][j]));
    rowmax[l] = m;
  }
#pragma unroll
  for (int l = 0; l < 8; ++l) {
    float m = rowmax[l];
#pragma unroll
    for (int off = 32; off > 0; off >>= 1) m = fmaxf(m, __shfl_xor(m, off));
    if (lane == 0) sred[l][wv] = m;
  }
  __syncthreads();
  if (tid < 8) {
    float mm = fmaxf(fmaxf(sred[tid][0], sred[tid][1]), fmaxf(sred[tid][2], sred[tid][3]));
    float s = 127.0f / fmaxf(mm, 1e-5f);
    sscale[tid] = s;
    srow[r0 + tid] = s;
  }
  __syncthreads();
  i8* qp = q + (size_t)r0 * 2048 + ch;
#pragma unroll
  for (int l = 0; l < 8; ++l) {
    float s = sscale[l];
    char4 c0q, c1q;
    c0q.x = (i8)fminf(fmaxf(rintf(y[l][0] * s), -128.f), 127.f);
    c0q.y = (i8)fminf(fmaxf(rintf(y[l][1] * s), -128.f), 127.f);
    c0q.z = (i8)fminf(fmaxf(rintf(y[l][2] * s), -128.f), 127.f);
    c0q.w = (i8)fminf(fmaxf(rintf(y[l][3] * s), -128.f), 127.f);
    c1q.x = (i8)fminf(fmaxf(rintf(y[l][4] * s), -128.f), 127.f);
    c1q.y = (i8)fminf(fmaxf(rintf(y[l][5] * s), -128.f), 127.f);
    c1q.z = (i8)fminf(fmaxf(rintf(y[l][6] * s), -128.f), 127.f);
    c1q.w = (i8)fminf(fmaxf(rintf(y[l][7] * s), -128.f), 127.f);
    *(char4*)(qp + l * 2048) = c0q;
    *(char4*)(qp + l * 2048 + 4) = c1q;
  }
}

// ---------------- GEMM3: 128x128, no-LDS, direct global->VGPR fragments, dbuf 1 tile ----------------
__global__ __launch_bounds__(512) void k_gemm3(const i8* __restrict__ q3, const i8* __restrict__ tout,
                                               const float* __restrict__ s3, const float* __restrict__ scales,
                                               float* __restrict__ out) {
  __shared__ float frow[128];
  const int tid = threadIdx.x;
  const int r0 = blockIdx.x * 128, c0 = blockIdx.y * 128;
  if (tid < 128) frow[tid] = scales[4] / s3[r0 + tid];
  __syncthreads();
  const int lane = tid & 63, wv = tid >> 6;
  const int wm = wv >> 1, wn = wv & 1;   // wave tile: rows wm*32, cols wn*64
  const int lo = lane & 15, hi = lane >> 4;
  int offA[2], offB[4];
#pragma unroll
  for (int m = 0; m < 2; ++m) offA[m] = (r0 + wm * 32 + m * 16 + lo) * 2048 + hi * 16;
#pragma unroll
  for (int n = 0; n < 4; ++n) offB[n] = (c0 + wn * 64 + n * 16 + lo) * 2048 + hi * 16;
  v4i acc[2][4];
#pragma unroll
  for (int m = 0; m < 2; ++m)
#pragma unroll
    for (int n = 0; n < 4; ++n) acc[m][n] = (v4i){0, 0, 0, 0};
  v4i a0[2], b0[4], a1[2], b1[4];

#define LD3(t, A, B)                                                            \
  {                                                                             \
    _Pragma("unroll") for (int m = 0; m < 2; ++m)                               \
        A[m] = *(const v4i*)(q3 + offA[m] + (t) * 64);                          \
    _Pragma("unroll") for (int n = 0; n < 4; ++n)                               \
        B[n] = *(const v4i*)(tout + offB[n] + (t) * 64);                        \
  }
#define FM3(A, B)                                                               \
  {                                                                             \
    _Pragma("unroll") for (int n = 0; n < 4; ++n)                               \
        _Pragma("unroll") for (int m = 0; m < 2; ++m)                           \
            acc[m][n] = MFMA_I8(A[m], B[n], acc[m][n], 0, 0, 0);                \
  }

  LD3(0, a0, b0);
#pragma unroll
  for (int t = 0; t < 32; t += 2) {
    if (t + 1 < 32) LD3(t + 1, a1, b1);
    FM3(a0, b0);
    if (t + 2 < 32) LD3(t + 2, a0, b0);
    if (t + 1 < 32) FM3(a1, b1);
  }
#undef LD3
#undef FM3

#pragma unroll
  for (int m = 0; m < 2; ++m)
#pragma unroll
    for (int n = 0; n < 4; ++n)
#pragma unroll
      for (int rg = 0; rg < 4; ++rg) {
        int row = wm * 32 + m * 16 + hi * 4 + rg;
        int col = wn * 64 + n * 16 + lo;
        out[(size_t)(r0 + row) * 1024 + c0 + col] = (float)acc[m][n][rg] * frow[row];
      }
}

extern "C" void kernel_launch(void* const* d_in, const int* in_sizes, int n_in,
                              void* d_out, int out_size, void* d_ws, size_t ws_size,
                              hipStream_t stream) {
  const float* x     = (const float*)d_in[0];
  const float* win   = (const float*)d_in[1];
  const float* cw    = (const float*)d_in[2];
  const float* cb    = (const float*)d_in[3];
  const float* dw    = (const float*)d_in[4];
  const float* dbias = (const float*)d_in[5];
  const float* bw    = (const float*)d_in[6];
  const float* cmw   = (const float*)d_in[7];
  const float* ow    = (const float*)d_in[8];
  const float* Dp    = (const float*)d_in[9];
  const float* logA  = (const float*)d_in[10];
  float* out = (float*)d_out;

  char* p = (char*)d_ws;
  float* gated = (float*)p;   p += (size_t)4096 * 2048 * 4;
  float* xin   = (float*)p;   p += (size_t)4096 * 2048 * 4;
  char* qx_rgn = p;           p += (size_t)4096 * 1024;
  char* tin_rgn = p;          p += (size_t)2 * 2048 * 1024;
  i8* tout = (i8*)p;          p += (size_t)1024 * 2048;
  i8* t2   = (i8*)p;          p += (size_t)48 * 2048;
  i8* q2   = (i8*)p;          p += (size_t)4096 * 2048;
  i8* q3   = (i8*)p;          p += (size_t)4096 * 2048;
  float* sx  = (float*)p;     p += (size_t)4096 * 4;
  float* s2  = (float*)p;     p += (size_t)4096 * 4;
  float* s3  = (float*)p;     p += (size_t)4096 * 4;
  float* scales = (float*)p;  p += 256;
  double* partial = (double*)p;

  i8* qx  = (i8*)qx_rgn;
  i8* tin = (i8*)tin_rgn;
  int* ipart = (int*)qx_rgn;
  float* At  = (float*)tin_rgn;
  float* dBt = At + 65536;
  float* Ct  = dBt + 65536;
  float* chb = Ct + 65536;

  k_abssum_all<<<432, 256, 0, stream>>>(win, dw, bw, cmw, ow, partial);
  k_finalize<<<1, 64, 0, stream>>>(partial, scales);
  k_wquant_all<<<6240, 256, 0, stream>>>(win, dw, bw, cmw, ow, scales, tin, t2, tout);

  k_actquant<1024><<<4096, 256, 0, stream>>>(x, qx, sx);
  k_gemm1<<<dim3(16, 16), 512, 0, stream>>>(qx, tin, sx, scales, gated);
  k_convq<<<512, 256, 0, stream>>>(gated, cw, cb, xin, q2, s2);
  k_gemm2<<<dim3(64, 2), 256, 0, stream>>>(q2, t2, ipart);
  k_xform<<<256, 256, 0, stream>>>(ipart, s2, scales, dbias, logA, At, dBt, Ct);
  k_scan<<<32, 256, 0, stream>>>(At, dBt, Ct, chb);
  k_yq<<<512, 256, 0, stream>>>(xin, chb, Dp, q3, s3);
  k_gemm3<<<dim3(32, 8), 512, 0, stream>>>(q3, tout, s3, scales, out);
}

// Round 8
// 152.722 us; speedup vs baseline: 1.3470x; 1.3470x over previous
//
#include <hip/hip_runtime.h>
#include <hip/hip_bf16.h>

typedef signed char i8;
typedef int v4i __attribute__((ext_vector_type(4)));

#define LSTR 80  // LDS row stride (bytes) for gemm2 staging
#define MFMA_I8 __builtin_amdgcn_mfma_i32_16x16x64_i8

__device__ __forceinline__ void gld16(const void* g, void* l) {
  __builtin_amdgcn_global_load_lds(
      (const __attribute__((address_space(1))) unsigned int*)g,
      (__attribute__((address_space(3))) unsigned int*)l, 16, 0, 0);
}

// pair-row swizzled LDS addr: two 64B rows per 128B line, chunk XOR by (rr>>1)&3
#define LADDR(rr, c) ((((rr) >> 1) << 7) + (((rr) & 1) << 6) + ((((c) ^ (((rr) >> 1) & 3))) << 4))

// ---------------- merged |w| abs-sum (fp64, deterministic layout) ----------------
__global__ __launch_bounds__(256) void k_abssum_all(const float* __restrict__ w0, const float* __restrict__ w1,
                                                    const float* __restrict__ w2, const float* __restrict__ w3,
                                                    const float* __restrict__ w4, double* __restrict__ partial) {
  int b = blockIdx.x;
  const float* w; int n, nb, bg;
  if (b < 256)      { w = w0; n = 4194304; nb = 256; bg = b; }
  else if (b < 272) { w = w1; n = 32768;   nb = 16;  bg = b - 256; }
  else if (b < 288) { w = w2; n = 32768;   nb = 16;  bg = b - 272; }
  else if (b < 304) { w = w3; n = 32768;   nb = 16;  bg = b - 288; }
  else              { w = w4; n = 2097152; nb = 128; bg = b - 304; }
  __shared__ double sd[256];
  double acc = 0.0;
  for (int i = bg * 256 + threadIdx.x; i < n; i += nb * 256) acc += (double)fabsf(w[i]);
  sd[threadIdx.x] = acc;
  __syncthreads();
  for (int s = 128; s > 0; s >>= 1) {
    if (threadIdx.x < s) sd[threadIdx.x] += sd[threadIdx.x + s];
    __syncthreads();
  }
  if (threadIdx.x == 0) partial[b] = sd[0];
}

__global__ void k_finalize(const double* __restrict__ partial, float* __restrict__ scales) {
  int m = threadIdx.x;
  if (m >= 5) return;
  const int off[6] = {0, 256, 272, 288, 304, 432};
  const double cnt[5] = {4194304.0, 32768.0, 32768.0, 32768.0, 2097152.0};
  double s = 0.0;
  for (int i = off[m]; i < off[m + 1]; ++i) s += partial[i];
  scales[m] = fmaxf((float)(s / cnt[m]), 1e-5f);
}

// ---------------- merged ternary weight quant ----------------
__global__ __launch_bounds__(256) void k_wquant_all(const float* __restrict__ w0, const float* __restrict__ w1,
                                                    const float* __restrict__ w2, const float* __restrict__ w3,
                                                    const float* __restrict__ w4, const float* __restrict__ scales,
                                                    i8* __restrict__ tin, i8* __restrict__ t2, i8* __restrict__ tout) {
  int b = blockIdx.x;
  const float* w; i8* t; int m, n;
  if (b < 4096)      { w = w0; t = tin;          m = 0; n = 4194304; }
  else if (b < 4128) { w = w1; t = t2;           m = 1; n = 32768; b -= 4096; }
  else if (b < 4160) { w = w2; t = t2 + 32768;   m = 2; n = 32768; b -= 4128; }
  else if (b < 4192) { w = w3; t = t2 + 65536;   m = 3; n = 32768; b -= 4160; }
  else               { w = w4; t = tout;         m = 4; n = 2097152; b -= 4192; }
  int idx = (b * 256 + threadIdx.x) * 4;
  if (idx >= n) return;
  float scale = scales[m];
  float4 v = *(const float4*)(w + idx);
  char4 q;
  q.x = (i8)fminf(fmaxf(rintf(v.x / scale), -1.f), 1.f);
  q.y = (i8)fminf(fmaxf(rintf(v.y / scale), -1.f), 1.f);
  q.z = (i8)fminf(fmaxf(rintf(v.z / scale), -1.f), 1.f);
  q.w = (i8)fminf(fmaxf(rintf(v.w / scale), -1.f), 1.f);
  *(char4*)(t + idx) = q;
}

// ---------------- per-row activation quant (bit-exact vs reference) ----------------
template <int W>
__global__ __launch_bounds__(256) void k_actquant(const float* __restrict__ x,
                                                  i8* __restrict__ q, float* __restrict__ srow) {
  constexpr int E = W / 256;
  const int r = blockIdx.x, tid = threadIdx.x;
  const float* xr = x + (size_t)r * W;
  float v[E];
  float m = 0.f;
#pragma unroll
  for (int j = 0; j < E; j += 4) {
    float4 t = *(const float4*)(xr + tid * E + j);
    v[j] = t.x; v[j + 1] = t.y; v[j + 2] = t.z; v[j + 3] = t.w;
    m = fmaxf(m, fmaxf(fmaxf(fabsf(t.x), fabsf(t.y)), fmaxf(fabsf(t.z), fabsf(t.w))));
  }
  __shared__ float sm[4];
  __shared__ float sbc;
#pragma unroll
  for (int off = 32; off > 0; off >>= 1) m = fmaxf(m, __shfl_xor(m, off));
  if ((tid & 63) == 0) sm[tid >> 6] = m;
  __syncthreads();
  if (tid == 0) {
    float mm = fmaxf(fmaxf(sm[0], sm[1]), fmaxf(sm[2], sm[3]));
    float s = 127.0f / fmaxf(mm, 1e-5f);
    sbc = s;
    srow[r] = s;
  }
  __syncthreads();
  float s = sbc;
#pragma unroll
  for (int j = 0; j < E; j += 4) {
    char4 c;
    c.x = (i8)fminf(fmaxf(rintf(v[j] * s), -128.f), 127.f);
    c.y = (i8)fminf(fmaxf(rintf(v[j + 1] * s), -128.f), 127.f);
    c.z = (i8)fminf(fmaxf(rintf(v[j + 2] * s), -128.f), 127.f);
    c.w = (i8)fminf(fmaxf(rintf(v[j + 3] * s), -128.f), 127.f);
    *(char4*)(q + (size_t)r * W + tid * E + j) = c;
  }
}

// ---------------- GEMM1: 128x(64|64), BK=64, dbuf, 4 waves, grid 1024 (4 blk/CU) ----------------
__global__ __launch_bounds__(256) void k_gemm1(const i8* __restrict__ qx, const i8* __restrict__ tin,
                                               const float* __restrict__ sx, const float* __restrict__ scales,
                                               float* __restrict__ gated) {
  __shared__ i8 A_[2][8192], G_[2][4096], V_[2][4096];
  __shared__ float frow[128];
  const int tid = threadIdx.x;
  const int r0 = blockIdx.x * 128, c0 = blockIdx.y * 64;
  if (tid < 128) frow[tid] = scales[0] / sx[r0 + tid];
  const int lane = tid & 63, wv = tid >> 6;
  const int wm = wv >> 1, wn = wv & 1;   // wave tile: rows wm*64 (64), cols wn*32 (32)
  const int lo = lane & 15, hi = lane >> 4;
  // staging source coords (linear dst d = tid*16; pair-row layout inverse)
  const int sr0 = ((tid >> 3) << 1) | ((tid >> 2) & 1);      // 0..63
  const int sc0 = ((tid & 3) ^ ((tid >> 3) & 3)) << 4;       // inverse-swizzled chunk
  const i8* gA0 = qx + (size_t)(r0 + sr0) * 1024 + sc0;
  const i8* gA1 = qx + (size_t)(r0 + 64 + sr0) * 1024 + sc0;
  const i8* gG  = tin + (size_t)(c0 + sr0) * 1024 + sc0;
  const i8* gV  = tin + (size_t)(2048 + c0 + sr0) * 1024 + sc0;
  const int ldsb = wv << 10;  // wave-uniform LDS base
  v4i accg[4][2], accv[4][2];
#pragma unroll
  for (int m = 0; m < 4; ++m)
#pragma unroll
    for (int n = 0; n < 2; ++n) {
      accg[m][n] = (v4i){0, 0, 0, 0};
      accv[m][n] = (v4i){0, 0, 0, 0};
    }

#define STAGE1(t, bi)                              \
  {                                                \
    const int kb = (t) << 6;                       \
    gld16(gA0 + kb, A_[bi] + ldsb);                \
    gld16(gA1 + kb, A_[bi] + 4096 + ldsb);         \
    gld16(gG + kb, G_[bi] + ldsb);                 \
    gld16(gV + kb, V_[bi] + ldsb);                 \
  }

#define COMPUTE1(bi)                                                                       \
  {                                                                                        \
    v4i a[4];                                                                              \
    _Pragma("unroll") for (int m = 0; m < 4; ++m)                                          \
        a[m] = *(const v4i*)&A_[bi][LADDR(wm * 64 + m * 16 + lo, hi)];                     \
    v4i bg0 = *(const v4i*)&G_[bi][LADDR(wn * 32 + lo, hi)];                               \
    v4i bg1 = *(const v4i*)&G_[bi][LADDR(wn * 32 + 16 + lo, hi)];                          \
    v4i bv0 = *(const v4i*)&V_[bi][LADDR(wn * 32 + lo, hi)];                               \
    v4i bv1 = *(const v4i*)&V_[bi][LADDR(wn * 32 + 16 + lo, hi)];                          \
    __builtin_amdgcn_s_setprio(1);                                                         \
    _Pragma("unroll") for (int m = 0; m < 4; ++m) {                                        \
      accg[m][0] = MFMA_I8(a[m], bg0, accg[m][0], 0, 0, 0);                                \
      accg[m][1] = MFMA_I8(a[m], bg1, accg[m][1], 0, 0, 0);                                \
      accv[m][0] = MFMA_I8(a[m], bv0, accv[m][0], 0, 0, 0);                                \
      accv[m][1] = MFMA_I8(a[m], bv1, accv[m][1], 0, 0, 0);                                \
    }                                                                                      \
    __builtin_amdgcn_s_setprio(0);                                                         \
  }

  STAGE1(0, 0);
  asm volatile("s_waitcnt vmcnt(0)" ::: "memory");
  __builtin_amdgcn_s_barrier();
#pragma unroll
  for (int t = 0; t < 16; ++t) {
    const int bi = t & 1;
    if (t + 1 < 16) STAGE1(t + 1, bi ^ 1);  // issue next-tile loads BEFORE compute
    COMPUTE1(bi);                           // MFMA hides load latency
    asm volatile("s_waitcnt vmcnt(0)" ::: "memory");
    __builtin_amdgcn_s_barrier();
  }
#undef STAGE1
#undef COMPUTE1

#pragma unroll
  for (int m = 0; m < 4; ++m)
#pragma unroll
    for (int n = 0; n < 2; ++n)
#pragma unroll
      for (int rg = 0; rg < 4; ++rg) {
        int row = wm * 64 + m * 16 + hi * 4 + rg;
        int col = wn * 32 + n * 16 + lo;
        float f = frow[row];
        float g = (float)accg[m][n][rg] * f;
        float v = (float)accv[m][n][rg] * f;
        float sg = 1.0f / (1.0f + expf(-g));
        gated[(size_t)(r0 + row) * 2048 + c0 + col] = g * sg * v;
      }
}

// ---------------- fused causal depthwise conv + act-quant, 8 rows/block, all-in-regs ----------------
__global__ __launch_bounds__(256) void k_convq(const float* __restrict__ g, const float* __restrict__ cw,
                                               const float* __restrict__ cb, float* __restrict__ xo,
                                               i8* __restrict__ q, float* __restrict__ srow) {
  const int tid = threadIdx.x;
  const int r0 = blockIdx.x * 8;
  const int l0 = r0 & 2047;
  const int ch = tid * 8;
  const int lane = tid & 63, wv = tid >> 6;
  float wt[4][8];
#pragma unroll
  for (int j = 0; j < 8; ++j) {
    float4 w = *(const float4*)(cw + (ch + j) * 4);
    wt[0][j] = w.x; wt[1][j] = w.y; wt[2][j] = w.z; wt[3][j] = w.w;
  }
  float bias[8];
  {
    float4 b0 = *(const float4*)(cb + ch), b1 = *(const float4*)(cb + ch + 4);
    bias[0] = b0.x; bias[1] = b0.y; bias[2] = b0.z; bias[3] = b0.w;
    bias[4] = b1.x; bias[5] = b1.y; bias[6] = b1.z; bias[7] = b1.w;
  }
  const float* gb = g + (size_t)r0 * 2048 + ch;
  float wm3[8], wm2[8], wm1[8];
  if (l0 != 0) {
    float4 a, b;
    a = *(const float4*)(gb - 3 * 2048); b = *(const float4*)(gb - 3 * 2048 + 4);
    wm3[0]=a.x; wm3[1]=a.y; wm3[2]=a.z; wm3[3]=a.w; wm3[4]=b.x; wm3[5]=b.y; wm3[6]=b.z; wm3[7]=b.w;
    a = *(const float4*)(gb - 2 * 2048); b = *(const float4*)(gb - 2 * 2048 + 4);
    wm2[0]=a.x; wm2[1]=a.y; wm2[2]=a.z; wm2[3]=a.w; wm2[4]=b.x; wm2[5]=b.y; wm2[6]=b.z; wm2[7]=b.w;
    a = *(const float4*)(gb - 1 * 2048); b = *(const float4*)(gb - 1 * 2048 + 4);
    wm1[0]=a.x; wm1[1]=a.y; wm1[2]=a.z; wm1[3]=a.w; wm1[4]=b.x; wm1[5]=b.y; wm1[6]=b.z; wm1[7]=b.w;
  } else {
#pragma unroll
    for (int j = 0; j < 8; ++j) { wm3[j] = 0.f; wm2[j] = 0.f; wm1[j] = 0.f; }
  }
  float* xop = xo + (size_t)r0 * 2048 + ch;
  float y[8][8];
  float rowmax[8];
#pragma unroll
  for (int l = 0; l < 8; ++l) {
    float cur[8];
    {
      float4 a = *(const float4*)(gb + l * 2048), b = *(const float4*)(gb + l * 2048 + 4);
      cur[0]=a.x; cur[1]=a.y; cur[2]=a.z; cur[3]=a.w; cur[4]=b.x; cur[5]=b.y; cur[6]=b.z; cur[7]=b.w;
    }
    float m = 0.f;
#pragma unroll
    for (int j = 0; j < 8; ++j) {
      float v = bias[j];
      v = fmaf(wt[0][j], wm3[j], v);
      v = fmaf(wt[1][j], wm2[j], v);
      v = fmaf(wt[2][j], wm1[j], v);
      v = fmaf(wt[3][j], cur[j], v);
      y[l][j] = v;
      m = fmaxf(m, fabsf(v));
    }
    rowmax[l] = m;
    *(float4*)(xop + l * 2048) = make_float4(y[l][0], y[l][1], y[l][2], y[l][3]);
    *(float4*)(xop + l * 2048 + 4) = make_float4(y[l][4], y[l][5], y[l][6], y[l][7]);
#pragma unroll
    for (int j = 0; j < 8; ++j) { wm3[j] = wm2[j]; wm2[j] = wm1[j]; wm1[j] = cur[j]; }
  }
  __shared__ float sred[8][4];
  __shared__ float sscale[8];
#pragma unroll
  for (int l = 0; l < 8; ++l) {
    float m = rowmax[l];
#pragma unroll
    for (int off = 32; off > 0; off >>= 1) m = fmaxf(m, __shfl_xor(m, off));
    if (lane == 0) sred[l][wv] = m;
  }
  __syncthreads();
  if (tid < 8) {
    float mm = fmaxf(fmaxf(sred[tid][0], sred[tid][1]), fmaxf(sred[tid][2], sred[tid][3]));
    float s = 127.0f / fmaxf(mm, 1e-5f);
    sscale[tid] = s;
    srow[r0 + tid] = s;
  }
  __syncthreads();
  i8* qp = q + (size_t)r0 * 2048 + ch;
#pragma unroll
  for (int l = 0; l < 8; ++l) {
    float s = sscale[l];
    char4 c0q, c1q;
    c0q.x = (i8)fminf(fmaxf(rintf(y[l][0] * s), -128.f), 127.f);
    c0q.y = (i8)fminf(fmaxf(rintf(y[l][1] * s), -128.f), 127.f);
    c0q.z = (i8)fminf(fmaxf(rintf(y[l][2] * s), -128.f), 127.f);
    c0q.w = (i8)fminf(fmaxf(rintf(y[l][3] * s), -128.f), 127.f);
    c1q.x = (i8)fminf(fmaxf(rintf(y[l][4] * s), -128.f), 127.f);
    c1q.y = (i8)fminf(fmaxf(rintf(y[l][5] * s), -128.f), 127.f);
    c1q.z = (i8)fminf(fmaxf(rintf(y[l][6] * s), -128.f), 127.f);
    c1q.w = (i8)fminf(fmaxf(rintf(y[l][7] * s), -128.f), 127.f);
    *(char4*)(qp + l * 2048) = c0q;
    *(char4*)(qp + l * 2048 + 4) = c1q;
  }
}

// ---------------- GEMM2: K-split i32 partials ----------------
__global__ __launch_bounds__(256) void k_gemm2(const i8* __restrict__ q2, const i8* __restrict__ t2,
                                               int* __restrict__ ipart) {
  __shared__ i8 As[64 * LSTR];
  __shared__ i8 Bs[48 * LSTR];
  const int tid = threadIdx.x;
  const int r0 = blockIdx.x * 64;
  const int kb = blockIdx.y * 1024;
  const int lrow = tid >> 2, lk = (tid & 3) * 16;
  const int lane = tid & 63, wv = tid >> 6;
  const int fr = lane & 15, fk = (lane >> 4) * 16;
  v4i acc[3];
#pragma unroll
  for (int s = 0; s < 3; ++s) acc[s] = (v4i){0, 0, 0, 0};
  for (int ks = 0; ks < 16; ++ks) {
    const int k0 = kb + ks * 64;
    __syncthreads();
    *(v4i*)&As[lrow * LSTR + lk] = *(const v4i*)&q2[(size_t)(r0 + lrow) * 2048 + k0 + lk];
    if (tid < 192)
      *(v4i*)&Bs[(tid >> 2) * LSTR + (tid & 3) * 16] = *(const v4i*)&t2[(size_t)(tid >> 2) * 2048 + k0 + (tid & 3) * 16];
    __syncthreads();
    v4i a = *(const v4i*)&As[(wv * 16 + fr) * LSTR + fk];
#pragma unroll
    for (int s = 0; s < 3; ++s) {
      v4i b = *(const v4i*)&Bs[(s * 16 + fr) * LSTR + fk];
      acc[s] = MFMA_I8(a, b, acc[s], 0, 0, 0);
    }
  }
#pragma unroll
  for (int s = 0; s < 3; ++s)
#pragma unroll
    for (int rg = 0; rg < 4; ++rg) {
      int row = wv * 16 + (lane >> 4) * 4 + rg;
      int col = s * 16 + (lane & 15);
      ipart[(size_t)blockIdx.y * 196608 + (size_t)(r0 + row) * 48 + col] = acc[s][rg];
    }
}

// ---------------- combine partials, dequant, build A_d / delta*B / C transposed ----------------
__global__ __launch_bounds__(256) void k_xform(const int* __restrict__ ip, const float* __restrict__ s2,
                                               const float* __restrict__ scales, const float* __restrict__ dbias,
                                               const float* __restrict__ logA, float* __restrict__ At,
                                               float* __restrict__ dBt, float* __restrict__ Ct) {
  int idx = blockIdx.x * 256 + threadIdx.x;
  int r = idx >> 4, n = idx & 15;
  int b = r >> 11, l = r & 2047;
  float fr = 1.0f / s2[r];
  int base = r * 48;
  float dd = (float)(ip[base + n] + ip[196608 + base + n]) * (scales[1] * fr) + dbias[n];
  float Bv = (float)(ip[base + 16 + n] + ip[196608 + base + 16 + n]) * (scales[2] * fr);
  float Cv = (float)(ip[base + 32 + n] + ip[196608 + base + 32 + n]) * (scales[3] * fr);
  int o = ((b * 16 + n) << 11) | l;
  At[o] = expf(dd * logA[n]);
  dBt[o] = dd * Bv;
  Ct[o] = Cv;
}

// ---------------- parallel scan over time per (b,n) ----------------
__global__ __launch_bounds__(256) void k_scan(const float* __restrict__ At, const float* __restrict__ dBt,
                                              const float* __restrict__ Ct, float* __restrict__ ch) {
  const int i = threadIdx.x;
  const int base = blockIdx.x << 11;
  float a[8], db[8], c[8];
  {
    const float4* p = (const float4*)(At + base + i * 8);
    float4 t0 = p[0], t1 = p[1];
    a[0]=t0.x; a[1]=t0.y; a[2]=t0.z; a[3]=t0.w; a[4]=t1.x; a[5]=t1.y; a[6]=t1.z; a[7]=t1.w;
  }
  {
    const float4* p = (const float4*)(dBt + base + i * 8);
    float4 t0 = p[0], t1 = p[1];
    db[0]=t0.x; db[1]=t0.y; db[2]=t0.z; db[3]=t0.w; db[4]=t1.x; db[5]=t1.y; db[6]=t1.z; db[7]=t1.w;
  }
  {
    const float4* p = (const float4*)(Ct + base + i * 8);
    float4 t0 = p[0], t1 = p[1];
    c[0]=t0.x; c[1]=t0.y; c[2]=t0.z; c[3]=t0.w; c[4]=t1.x; c[5]=t1.y; c[6]=t1.z; c[7]=t1.w;
  }
  float Ac = 1.f, Bc = 0.f;
#pragma unroll
  for (int j = 0; j < 8; ++j) { Bc = a[j] * Bc + db[j]; Ac *= a[j]; }
  __shared__ float sA[256], sB[256];
  sA[i] = Ac; sB[i] = Bc;
  __syncthreads();
  for (int off = 1; off < 256; off <<= 1) {
    float pA = 1.f, pB = 0.f;
    if (i >= off) { pA = sA[i - off]; pB = sB[i - off]; }
    __syncthreads();
    Bc = Ac * pB + Bc;
    Ac = Ac * pA;
    sA[i] = Ac; sB[i] = Bc;
    __syncthreads();
  }
  float h = (i > 0) ? sB[i - 1] : 0.f;
  float o[8];
#pragma unroll
  for (int j = 0; j < 8; ++j) { h = a[j] * h + db[j]; o[j] = c[j] * h; }
  float4* po = (float4*)(ch + base + i * 8);
  po[0] = make_float4(o[0], o[1], o[2], o[3]);
  po[1] = make_float4(o[4], o[5], o[6], o[7]);
}

// ---------------- y_inner scaling + act-quant, 8 rows/block, all-in-regs ----------------
__global__ __launch_bounds__(256) void k_yq(const float* __restrict__ xin, const float* __restrict__ chb,
                                            const float* __restrict__ Dp, i8* __restrict__ q,
                                            float* __restrict__ srow) {
  const int tid = threadIdx.x;
  const int r0 = blockIdx.x * 8;
  const int b = r0 >> 11, l0 = r0 & 2047;
  const int lane = tid & 63, wv = tid >> 6;
  __shared__ float ssig[8 * 16];
  __shared__ float ssg[8];
  __shared__ float sred[8][4];
  __shared__ float sscale[8];
  if (tid < 128) {
    int n = tid >> 3, li = tid & 7;
    ssig[li * 16 + n] = chb[((size_t)(b * 16 + n) << 11) | (l0 + li)];
  }
  __syncthreads();
  if (tid < 8) {
    float s = 0.f;
    for (int n = 0; n < 16; ++n) s += ssig[tid * 16 + n];
    ssg[tid] = 1.0f / (1.0f + expf(-s));
  }
  __syncthreads();
  const int ch = tid * 8;
  float dreg[8];
  {
    float4 d0 = *(const float4*)(Dp + ch), d1 = *(const float4*)(Dp + ch + 4);
    dreg[0]=d0.x; dreg[1]=d0.y; dreg[2]=d0.z; dreg[3]=d0.w;
    dreg[4]=d1.x; dreg[5]=d1.y; dreg[6]=d1.z; dreg[7]=d1.w;
  }
  const float* xr = xin + (size_t)r0 * 2048 + ch;
  float y[8][8];
  float rowmax[8];
#pragma unroll
  for (int l = 0; l < 8; ++l) {
    float sg = ssg[l];
    float4 a = *(const float4*)(xr + l * 2048);
    float4 c = *(const float4*)(xr + l * 2048 + 4);
    y[l][0] = a.x * (sg + dreg[0]);
    y[l][1] = a.y * (sg + dreg[1]);
    y[l][2] = a.z * (sg + dreg[2]);
    y[l][3] = a.w * (sg + dreg[3]);
    y[l][4] = c.x * (sg + dreg[4]);
    y[l][5] = c.y * (sg + dreg[5]);
    y[l][6] = c.z * (sg + dreg[6]);
    y[l][7] = c.w * (sg + dreg[7]);
    float m = 0.f;
#pragma unroll
    for (int j = 0; j < 8; ++j) m = fmaxf(m, fabsf(y[l][j]));
    rowmax[l] = m;
  }
#pragma unroll
  for (int l = 0; l < 8; ++l) {
    float m = rowmax[l];
#pragma unroll
    for (int off = 32; off > 0; off >>= 1) m = fmaxf(m, __shfl_xor(m, off));
    if (lane == 0) sred[l][wv] = m;
  }
  __syncthreads();
  if (tid < 8) {
    float mm = fmaxf(fmaxf(sred[tid][0], sred[tid][1]), fmaxf(sred[tid][2], sred[tid][3]));
    float s = 127.0f / fmaxf(mm, 1e-5f);
    sscale[tid] = s;
    srow[r0 + tid] = s;
  }
  __syncthreads();
  i8* qp = q + (size_t)r0 * 2048 + ch;
#pragma unroll
  for (int l = 0; l < 8; ++l) {
    float s = sscale[l];
    char4 c0q, c1q;
    c0q.x = (i8)fminf(fmaxf(rintf(y[l][0] * s), -128.f), 127.f);
    c0q.y = (i8)fminf(fmaxf(rintf(y[l][1] * s), -128.f), 127.f);
    c0q.z = (i8)fminf(fmaxf(rintf(y[l][2] * s), -128.f), 127.f);
    c0q.w = (i8)fminf(fmaxf(rintf(y[l][3] * s), -128.f), 127.f);
    c1q.x = (i8)fminf(fmaxf(rintf(y[l][4] * s), -128.f), 127.f);
    c1q.y = (i8)fminf(fmaxf(rintf(y[l][5] * s), -128.f), 127.f);
    c1q.z = (i8)fminf(fmaxf(rintf(y[l][6] * s), -128.f), 127.f);
    c1q.w = (i8)fminf(fmaxf(rintf(y[l][7] * s), -128.f), 127.f);
    *(char4*)(qp + l * 2048) = c0q;
    *(char4*)(qp + l * 2048 + 4) = c1q;
  }
}

// ---------------- GEMM3: 128x128 tile, BK=64, 8 waves, phase-interleaved pipeline ----------------
__global__ __launch_bounds__(512) void k_gemm3(const i8* __restrict__ q3, const i8* __restrict__ tout,
                                               const float* __restrict__ s3, const float* __restrict__ scales,
                                               float* __restrict__ out) {
  __shared__ i8 A_[2][8192], B_[2][8192];
  __shared__ float frow[128];
  const int tid = threadIdx.x;
  const int r0 = blockIdx.x * 128, c0 = blockIdx.y * 128;
  if (tid < 128) frow[tid] = scales[4] / s3[r0 + tid];
  const int lane = tid & 63, wv = tid >> 6;
  const int wm = wv >> 1, wn = wv & 1;   // wave tile: rows wm*32, cols wn*64
  const int lo = lane & 15, hi = lane >> 4;
  const int d0 = tid << 4;
  const int sr0 = ((d0 >> 7) << 1) | ((d0 >> 6) & 1);           // 0..127
  const int sc0 = ((((d0 >> 4) & 3) ^ ((sr0 >> 1) & 3)) << 4);
  const i8* gA = q3 + (size_t)(r0 + sr0) * 2048 + sc0;
  const i8* gB = tout + (size_t)(c0 + sr0) * 2048 + sc0;
  const int ldsb = wv << 10;
  v4i acc[2][4];
#pragma unroll
  for (int m = 0; m < 2; ++m)
#pragma unroll
    for (int n = 0; n < 4; ++n) acc[m][n] = (v4i){0, 0, 0, 0};

#define STAGE3(t, bi)                       \
  {                                         \
    const int kb = (t) << 6;                \
    gld16(gA + kb, A_[bi] + ldsb);          \
    gld16(gB + kb, B_[bi] + ldsb);          \
  }

  STAGE3(0, 0);
  for (int t = 0; t < 32; ++t) {
    const int bi = t & 1;
    if (t < 31) {
      STAGE3(t + 1, bi ^ 1);
      asm volatile("s_waitcnt vmcnt(2)" ::: "memory");
    } else {
      asm volatile("s_waitcnt vmcnt(0)" ::: "memory");
    }
    __builtin_amdgcn_s_barrier();
    v4i a[2];
#pragma unroll
    for (int m = 0; m < 2; ++m) a[m] = *(const v4i*)&A_[bi][LADDR(wm * 32 + m * 16 + lo, hi)];
    v4i b0 = *(const v4i*)&B_[bi][LADDR(wn * 64 + lo, hi)];
    v4i b1 = *(const v4i*)&B_[bi][LADDR(wn * 64 + 16 + lo, hi)];
    __builtin_amdgcn_s_barrier();
    __builtin_amdgcn_s_setprio(1);
#pragma unroll
    for (int m = 0; m < 2; ++m) {
      acc[m][0] = MFMA_I8(a[m], b0, acc[m][0], 0, 0, 0);
      acc[m][1] = MFMA_I8(a[m], b1, acc[m][1], 0, 0, 0);
    }
    __builtin_amdgcn_s_setprio(0);
    __builtin_amdgcn_s_barrier();
    b0 = *(const v4i*)&B_[bi][LADDR(wn * 64 + 32 + lo, hi)];
    b1 = *(const v4i*)&B_[bi][LADDR(wn * 64 + 48 + lo, hi)];
    __builtin_amdgcn_s_barrier();
    __builtin_amdgcn_s_setprio(1);
#pragma unroll
    for (int m = 0; m < 2; ++m) {
      acc[m][2] = MFMA_I8(a[m], b0, acc[m][2], 0, 0, 0);
      acc[m][3] = MFMA_I8(a[m], b1, acc[m][3], 0, 0, 0);
    }
    __builtin_amdgcn_s_setprio(0);
    __builtin_amdgcn_s_barrier();
  }
#undef STAGE3

#pragma unroll
  for (int m = 0; m < 2; ++m)
#pragma unroll
    for (int n = 0; n < 4; ++n)
#pragma unroll
      for (int rg = 0; rg < 4; ++rg) {
        int row = wm * 32 + m * 16 + hi * 4 + rg;
        int col = wn * 64 + n * 16 + lo;
        out[(size_t)(r0 + row) * 1024 + c0 + col] = (float)acc[m][n][rg] * frow[row];
      }
}

extern "C" void kernel_launch(void* const* d_in, const int* in_sizes, int n_in,
                              void* d_out, int out_size, void* d_ws, size_t ws_size,
                              hipStream_t stream) {
  const float* x     = (const float*)d_in[0];
  const float* win   = (const float*)d_in[1];
  const float* cw    = (const float*)d_in[2];
  const float* cb    = (const float*)d_in[3];
  const float* dw    = (const float*)d_in[4];
  const float* dbias = (const float*)d_in[5];
  const float* bw    = (const float*)d_in[6];
  const float* cmw   = (const float*)d_in[7];
  const float* ow    = (const float*)d_in[8];
  const float* Dp    = (const float*)d_in[9];
  const float* logA  = (const float*)d_in[10];
  float* out = (float*)d_out;

  char* p = (char*)d_ws;
  float* gated = (float*)p;   p += (size_t)4096 * 2048 * 4;
  float* xin   = (float*)p;   p += (size_t)4096 * 2048 * 4;
  char* qx_rgn = p;           p += (size_t)4096 * 1024;
  char* tin_rgn = p;          p += (size_t)2 * 2048 * 1024;
  i8* tout = (i8*)p;          p += (size_t)1024 * 2048;
  i8* t2   = (i8*)p;          p += (size_t)48 * 2048;
  i8* q2   = (i8*)p;          p += (size_t)4096 * 2048;
  i8* q3   = (i8*)p;          p += (size_t)4096 * 2048;
  float* sx  = (float*)p;     p += (size_t)4096 * 4;
  float* s2  = (float*)p;     p += (size_t)4096 * 4;
  float* s3  = (float*)p;     p += (size_t)4096 * 4;
  float* scales = (float*)p;  p += 256;
  double* partial = (double*)p;

  i8* qx  = (i8*)qx_rgn;
  i8* tin = (i8*)tin_rgn;
  int* ipart = (int*)qx_rgn;
  float* At  = (float*)tin_rgn;
  float* dBt = At + 65536;
  float* Ct  = dBt + 65536;
  float* chb = Ct + 65536;

  k_abssum_all<<<432, 256, 0, stream>>>(win, dw, bw, cmw, ow, partial);
  k_finalize<<<1, 64, 0, stream>>>(partial, scales);
  k_wquant_all<<<6240, 256, 0, stream>>>(win, dw, bw, cmw, ow, scales, tin, t2, tout);

  k_actquant<1024><<<4096, 256, 0, stream>>>(x, qx, sx);
  k_gemm1<<<dim3(32, 32), 256, 0, stream>>>(qx, tin, sx, scales, gated);
  k_convq<<<512, 256, 0, stream>>>(gated, cw, cb, xin, q2, s2);
  k_gemm2<<<dim3(64, 2), 256, 0, stream>>>(q2, t2, ipart);
  k_xform<<<256, 256, 0, stream>>>(ipart, s2, scales, dbias, logA, At, dBt, Ct);
  k_scan<<<32, 256, 0, stream>>>(At, dBt, Ct, chb);
  k_yq<<<512, 256, 0, stream>>>(xin, chb, Dp, q3, s3);
  k_gemm3<<<dim3(32, 8), 512, 0, stream>>>(q3, tout, s3, scales, out);
}